// Round 11
// baseline (476.641 us; speedup 1.0000x reference)
//
#include <hip/hip_runtime.h>

// B=8, N=128, COOR=3, F=128, FILT=128
#define BB   8
#define NN   128
#define FF   128
#define KK   128

typedef float f32x4 __attribute__((ext_vector_type(4)));

// ===========================================================================
// DIAGNOSTIC ROUND. Output is bit-identical to R10; each kernel internally
// repeats its work (pointers laundered via asm so the compiler cannot CSE
// the loads or DSE the redundant stores) so that BOTH dispatches exceed the
// harness fill kernels (~40-45us) and appear in the rocprof top-5 with their
// own dur_us / FETCH_SIZE / WRITE_SIZE / timestamps.
//   k_pre_diag : 32x repeat  -> P = dur/32
//   k_main_diag: 1x compute + 6x NT-store passes -> NT write BW = hbm_bytes/dur
//   timestamp gap between the two dispatches = inter-kernel launch gap
// ===========================================================================

__global__ __launch_bounds__(256) void k_pre_diag(const float* __restrict__ vf,
                                                  const float* __restrict__ w,
                                                  const float* __restrict__ bias,
                                                  float* __restrict__ ac) {
    const int bn0 = blockIdx.x * 2;
    const int tid = threadIdx.x;
    const int col  = tid & 127;
    const int half = tid >> 7;                     // 0 = A-half, 1 = C-half
    const float hb = 0.5f * bias[col];

    for (int o = 0; o < 32; ++o) {
        const float* wcol = w + half * (FF * KK) + col;
        const float* vr   = vf + (size_t)bn0 * 384;
        float* dst = ac + (size_t)bn0 * 768 + half * 128 + col;
        // Launder: loads can't be CSE'd across o, stores can't be DSE'd.
        asm volatile("" : "+v"(wcol));
        asm volatile("" : "+s"(vr));
        asm volatile("" : "+v"(dst));

        float a00 = 0.f, a01 = 0.f, a02 = 0.f;
        float a10 = 0.f, a11 = 0.f, a12 = 0.f;
#pragma unroll 8
        for (int f = 0; f < FF; ++f) {
            const float wv = wcol[f * KK];
            a00 = fmaf(wv, vr[f],       a00);
            a01 = fmaf(wv, vr[128 + f], a01);
            a02 = fmaf(wv, vr[256 + f], a02);
            a10 = fmaf(wv, vr[384 + f], a10);
            a11 = fmaf(wv, vr[512 + f], a11);
            a12 = fmaf(wv, vr[640 + f], a12);
        }
        dst[0]    = a00 + hb;  dst[256]  = a01 + hb;  dst[512]  = a02 + hb;
        dst[768]  = a10 + hb;  dst[1024] = a11 + hb;  dst[1280] = a12 + hb;
    }
}

__global__ __launch_bounds__(256) void k_main_diag(const float* __restrict__ dist,
                                                   const float* __restrict__ ac,
                                                   float* __restrict__ out) {
    const int bx  = blockIdx.x;
    const int b   = bx >> 8;            // 256 blocks per batch
    const int rem = bx & 255;
    const int it  = rem >> 3;           // 0..31
    const int jt  = rem & 7;            // 0..7
    const int i0  = it * 4, j0 = jt * 16;
    const int tid = threadIdx.x;

    __shared__ float dl[192];           // [ti][jj][c] = 4 x 16 x 3
    if (tid < 192) {
        const int ti = tid / 48, r = tid % 48;
        dl[tid] = dist[((size_t)(b * NN + i0 + ti) * NN + j0) * 3 + r];
    }
    __syncthreads();

    const int k4 = tid & 31;
    const int rg = tid >> 5;            // 0..7
    const int ti = rg >> 1;             // 0..3, constant per WAVE
    const int jp = rg & 1;              // j parity within wave
    const int i  = i0 + ti;

    const float4* arow = (const float4*)(ac + (size_t)(b * NN + i) * 768) + k4;
    const float4 a0 = arow[0], a1 = arow[64], a2 = arow[128];
    float* obase = out + (size_t)(b * NN + i) * NN * KK;
    const float* dlt = dl + ti * 48;

    // Compute all 8 results once into registers (R10 math exactly).
    f32x4 res[8];
#pragma unroll
    for (int p = 0; p < 8; ++p) {
        const int jj = 2 * p + jp;
        const int j  = j0 + jj;
        const float d0 = dlt[jj * 3], d1 = dlt[jj * 3 + 1], d2 = dlt[jj * 3 + 2];

        const float4* crow = (const float4*)(ac + (size_t)(b * NN + j) * 768)
                             + 32 + k4;          // +128 floats: C-half
        const float4 c0 = crow[0], c1 = crow[64], c2 = crow[128];

        f32x4 r;
        r.x = fmaf(d0, a0.x + c0.x, fmaf(d1, a1.x + c1.x, d2 * (a2.x + c2.x)));
        r.y = fmaf(d0, a0.y + c0.y, fmaf(d1, a1.y + c1.y, d2 * (a2.y + c2.y)));
        r.z = fmaf(d0, a0.z + c0.z, fmaf(d1, a1.z + c1.z, d2 * (a2.z + c2.z)));
        r.w = fmaf(d0, a0.w + c0.w, fmaf(d1, a1.w + c1.w, d2 * (a2.w + c2.w)));
        res[p] = r;
    }

    // 6 NT-store passes of the SAME values to the SAME addresses (laundered
    // base pointer per pass -> no DSE). Pass 6's values are final & correct.
    for (int o = 0; o < 6; ++o) {
        float* ob = obase;
        asm volatile("" : "+v"(ob));
#pragma unroll
        for (int p = 0; p < 8; ++p) {
            const int jj = 2 * p + jp;
            __builtin_nontemporal_store(res[p],
                (f32x4*)(ob + (size_t)(j0 + jj) * KK + k4 * 4));
        }
    }
}

// ---------------------------------------------------------------------------
// Fallback (only if ws_size < 3 MB): fused, recomputes C per j. Slow but correct.
// ---------------------------------------------------------------------------
__global__ __launch_bounds__(256) void k_fused_slow(const float* __restrict__ vf,
                                                    const float* __restrict__ dist,
                                                    const float* __restrict__ w,
                                                    const float* __restrict__ bias,
                                                    float* __restrict__ out) {
    const int bi  = blockIdx.x;           // b*NN + i
    const int b   = bi >> 7;
    const int tid = threadIdx.x;
    __shared__ float arow[384];
    __shared__ float crow[384];

    for (int idx = tid; idx < 384; idx += 256) {
        const int c = idx >> 7, k = idx & 127;
        const float* v = vf + (size_t)bi * 384 + c * 128;
        float s = 0.f;
        for (int f = 0; f < 128; ++f) s = fmaf(v[f], w[f * 128 + k], s);
        arow[idx] = s;
    }
    __syncthreads();

    for (int j = 0; j < NN; ++j) {
        for (int idx = tid; idx < 384; idx += 256) {
            const int c = idx >> 7, k = idx & 127;
            const float* v = vf + (size_t)(b * NN + j) * 384 + c * 128;
            float s = 0.f;
            for (int f = 0; f < 128; ++f) s = fmaf(v[f], w[(128 + f) * 128 + k], s);
            crow[idx] = s;
        }
        __syncthreads();
        if (tid < 128) {
            const float* dj = dist + ((size_t)bi * NN + j) * 3;
            const float d0 = dj[0], d1 = dj[1], d2 = dj[2];
            const float sd = d0 + d1 + d2;
            const float r = fmaf(d0, arow[tid] + crow[tid],
                            fmaf(d1, arow[128 + tid] + crow[128 + tid],
                            fmaf(d2, arow[256 + tid] + crow[256 + tid], sd * bias[tid])));
            out[((size_t)bi * NN + j) * 128 + tid] = r;
        }
        __syncthreads();
    }
}

extern "C" void kernel_launch(void* const* d_in, const int* in_sizes, int n_in,
                              void* d_out, int out_size, void* d_ws, size_t ws_size,
                              hipStream_t stream) {
    const float* vf   = (const float*)d_in[0];   // [8,128,3,128]
    const float* dist = (const float*)d_in[1];   // [8,128,128,3]
    const float* w    = (const float*)d_in[2];   // [256,128]
    const float* bias = (const float*)d_in[3];   // [128]
    float* out = (float*)d_out;                  // [8,128,128,128]

    const size_t need = (size_t)BB * NN * 3 * 256 * sizeof(float);  // 3 MB
    if (ws_size >= need) {
        float* ac = (float*)d_ws;
        k_pre_diag<<<512, 256, 0, stream>>>(vf, w, bias, ac);
        k_main_diag<<<2048, 256, 0, stream>>>(dist, ac, out);
    } else {
        k_fused_slow<<<BB * NN, 256, 0, stream>>>(vf, dist, w, bias, out);
    }
}

// Round 12
// 25.753 us; speedup vs baseline: 18.5084x; 18.5084x over previous
//
#include <hip/hip_runtime.h>

// B=8, N=128, COOR=3, F=128, FILT=128
#define BB   8
#define NN   128
#define FF   128
#define KK   128

typedef float f32x4 __attribute__((ext_vector_type(4)));

// ---------------------------------------------------------------------------
// Kernel 1: AC[bn][c][2x128]: per (bn,c): [A+bias/2 (128) | C+bias/2 (128)]
//   A[bn,c,k] = sum_f vf[bn,c,f] * w[f,k],  C uses w[128+f,k].
// R11 diag: old k_pre = 13.8us, latency-bound (VALUBusy 26%, 2 waves/SIMD).
// Fix: 512-thr blocks, f split in half across thread-halves (fh), 64 f-iters
// per thread, cross-fh LDS reduce. Grid 512 -> 16 waves/CU = 4/SIMD (2x the
// latency cover), same reuse-6 (2bn x 3coor per w-scalar), unroll 16.
// ---------------------------------------------------------------------------
__global__ __launch_bounds__(512) void k_pre(const float* __restrict__ vf,
                                             const float* __restrict__ w,
                                             const float* __restrict__ bias,
                                             float* __restrict__ ac) {
    const int bn0 = blockIdx.x * 2;
    const int tid = threadIdx.x;
    const int col  = tid & 127;
    const int half = (tid >> 7) & 1;    // 0 = A-half, 1 = C-half
    const int fh   = tid >> 8;          // f-half: wave-uniform by construction
    const int fh_s = __builtin_amdgcn_readfirstlane(fh);  // pin scalar pipe

    __shared__ float red[256][6];       // fh=1 partials: [slot][r*3+c]

    const float* wcol = w + half * (FF * KK) + (size_t)fh_s * 64 * KK + col;
    const float* vr   = vf + (size_t)bn0 * 384 + fh_s * 64;  // wave-uniform

    float a0 = 0.f, a1 = 0.f, a2 = 0.f, a3 = 0.f, a4 = 0.f, a5 = 0.f;
#pragma unroll 16
    for (int f = 0; f < 64; ++f) {
        const float wv = wcol[(size_t)f * KK];
        a0 = fmaf(wv, vr[f],       a0);
        a1 = fmaf(wv, vr[128 + f], a1);
        a2 = fmaf(wv, vr[256 + f], a2);
        a3 = fmaf(wv, vr[384 + f], a3);
        a4 = fmaf(wv, vr[512 + f], a4);
        a5 = fmaf(wv, vr[640 + f], a5);
    }

    const int slot = tid & 255;         // (half, col)
    if (fh) {
        red[slot][0] = a0; red[slot][1] = a1; red[slot][2] = a2;
        red[slot][3] = a3; red[slot][4] = a4; red[slot][5] = a5;
    }
    __syncthreads();
    if (!fh) {
        const float hb = 0.5f * bias[col];
        float* dst = ac + (size_t)bn0 * 768 + half * 128 + col;
        dst[0]    = a0 + red[slot][0] + hb;
        dst[256]  = a1 + red[slot][1] + hb;
        dst[512]  = a2 + red[slot][2] + hb;
        dst[768]  = a3 + red[slot][3] + hb;
        dst[1024] = a4 + red[slot][4] + hb;
        dst[1280] = a5 + red[slot][5] + hb;
    }
}

// ---------------------------------------------------------------------------
// Kernel 2: out[b,i,j,k] = sum_c d[b,i,j,c] * (A'[b,i,c,k] + C'[b,j,c,k])
// R10 version byte-identical (best known: grid 2048, dist-LDS, wave-uniform
// i with contiguous 1 KB wave stores, full unroll, NT stores).
// ---------------------------------------------------------------------------
__global__ __launch_bounds__(256) void k_main(const float* __restrict__ dist,
                                              const float* __restrict__ ac,
                                              float* __restrict__ out) {
    const int bx  = blockIdx.x;
    const int b   = bx >> 8;            // 256 blocks per batch
    const int rem = bx & 255;
    const int it  = rem >> 3;           // 0..31
    const int jt  = rem & 7;            // 0..7 (low bits -> XCD affinity on C)
    const int i0  = it * 4, j0 = jt * 16;
    const int tid = threadIdx.x;

    __shared__ float dl[192];           // [ti][jj][c] = 4 x 16 x 3
    if (tid < 192) {
        const int ti = tid / 48, r = tid % 48;
        dl[tid] = dist[((size_t)(b * NN + i0 + ti) * NN + j0) * 3 + r];
    }
    __syncthreads();

    const int k4 = tid & 31;
    const int rg = tid >> 5;            // 0..7
    const int ti = rg >> 1;             // 0..3, constant per WAVE
    const int jp = rg & 1;              // j parity within wave
    const int i  = i0 + ti;

    const float4* arow = (const float4*)(ac + (size_t)(b * NN + i) * 768) + k4;
    const float4 a0 = arow[0], a1 = arow[64], a2 = arow[128];
    float* obase = out + (size_t)(b * NN + i) * NN * KK;
    const float* dlt = dl + ti * 48;

#pragma unroll
    for (int p = 0; p < 8; ++p) {
        const int jj = 2 * p + jp;
        const int j  = j0 + jj;
        const float d0 = dlt[jj * 3], d1 = dlt[jj * 3 + 1], d2 = dlt[jj * 3 + 2];

        const float4* crow = (const float4*)(ac + (size_t)(b * NN + j) * 768)
                             + 32 + k4;          // +128 floats: C-half
        const float4 c0 = crow[0], c1 = crow[64], c2 = crow[128];

        f32x4 r;
        r.x = fmaf(d0, a0.x + c0.x, fmaf(d1, a1.x + c1.x, d2 * (a2.x + c2.x)));
        r.y = fmaf(d0, a0.y + c0.y, fmaf(d1, a1.y + c1.y, d2 * (a2.y + c2.y)));
        r.z = fmaf(d0, a0.z + c0.z, fmaf(d1, a1.z + c1.z, d2 * (a2.z + c2.z)));
        r.w = fmaf(d0, a0.w + c0.w, fmaf(d1, a1.w + c1.w, d2 * (a2.w + c2.w)));

        __builtin_nontemporal_store(r, (f32x4*)(obase + (size_t)j * KK + k4 * 4));
    }
}

// ---------------------------------------------------------------------------
// Fallback (only if ws_size < 3 MB): fused, recomputes C per j. Slow but correct.
// ---------------------------------------------------------------------------
__global__ __launch_bounds__(256) void k_fused_slow(const float* __restrict__ vf,
                                                    const float* __restrict__ dist,
                                                    const float* __restrict__ w,
                                                    const float* __restrict__ bias,
                                                    float* __restrict__ out) {
    const int bi  = blockIdx.x;           // b*NN + i
    const int b   = bi >> 7;
    const int tid = threadIdx.x;
    __shared__ float arow[384];
    __shared__ float crow[384];

    for (int idx = tid; idx < 384; idx += 256) {
        const int c = idx >> 7, k = idx & 127;
        const float* v = vf + (size_t)bi * 384 + c * 128;
        float s = 0.f;
        for (int f = 0; f < 128; ++f) s = fmaf(v[f], w[f * 128 + k], s);
        arow[idx] = s;
    }
    __syncthreads();

    for (int j = 0; j < NN; ++j) {
        for (int idx = tid; idx < 384; idx += 256) {
            const int c = idx >> 7, k = idx & 127;
            const float* v = vf + (size_t)(b * NN + j) * 384 + c * 128;
            float s = 0.f;
            for (int f = 0; f < 128; ++f) s = fmaf(v[f], w[(128 + f) * 128 + k], s);
            crow[idx] = s;
        }
        __syncthreads();
        if (tid < 128) {
            const float* dj = dist + ((size_t)bi * NN + j) * 3;
            const float d0 = dj[0], d1 = dj[1], d2 = dj[2];
            const float sd = d0 + d1 + d2;
            const float r = fmaf(d0, arow[tid] + crow[tid],
                            fmaf(d1, arow[128 + tid] + crow[128 + tid],
                            fmaf(d2, arow[256 + tid] + crow[256 + tid], sd * bias[tid])));
            out[((size_t)bi * NN + j) * 128 + tid] = r;
        }
        __syncthreads();
    }
}

extern "C" void kernel_launch(void* const* d_in, const int* in_sizes, int n_in,
                              void* d_out, int out_size, void* d_ws, size_t ws_size,
                              hipStream_t stream) {
    const float* vf   = (const float*)d_in[0];   // [8,128,3,128]
    const float* dist = (const float*)d_in[1];   // [8,128,128,3]
    const float* w    = (const float*)d_in[2];   // [256,128]
    const float* bias = (const float*)d_in[3];   // [128]
    float* out = (float*)d_out;                  // [8,128,128,128]

    const size_t need = (size_t)BB * NN * 3 * 256 * sizeof(float);  // 3 MB
    if (ws_size >= need) {
        float* ac = (float*)d_ws;
        k_pre<<<512, 512, 0, stream>>>(vf, w, bias, ac);
        k_main<<<2048, 256, 0, stream>>>(dist, ac, out);
    } else {
        k_fused_slow<<<BB * NN, 256, 0, stream>>>(vf, dist, w, bias, out);
    }
}